// Round 4
// baseline (1591.642 us; speedup 1.0000x reference)
//
#include <hip/hip_runtime.h>

// Problem constants (match reference)
constexpr int   N_NODES = 80000;
constexpr int   N_EDGE  = 2560000;
constexpr int   IN_DIM  = 128;
constexpr int   H1      = 32;
constexpr int   H2      = 64;
constexpr int   NPB     = 10000;   // nodes per batch
constexpr int   NB      = 8;       // batches

// ---------------- init: ecnt = 0, partial = 0 ----------------
__global__ void k_init(unsigned* __restrict__ ecnt, double* __restrict__ partial) {
    int i = blockIdx.x * blockDim.x + threadIdx.x;
    if (i < N_NODES) ecnt[i] = 0u;
    if (i < NB) partial[i] = 0.0;
}

// ---------------- degree count (edges only): ecnt[dst]++ ----------------
__global__ void k_deg(const int* __restrict__ ei, unsigned* __restrict__ ecnt) {
    int e = blockIdx.x * blockDim.x + threadIdx.x;
    if (e >= N_EDGE) return;
    atomicAdd(&ecnt[ei[N_EDGE + e]], 1u);
}

// ---------------- dinv = rsqrt(ecnt + 1)  (+1 = self loop) ----------------
__global__ void k_dinv(const unsigned* __restrict__ ecnt, float* __restrict__ dinv) {
    int i = blockIdx.x * blockDim.x + threadIdx.x;
    if (i < N_NODES) dinv[i] = rsqrtf((float)(ecnt[i] + 1u));
}

// ------- exclusive scan of ecnt -> row_ptr, bump (single block, C=80) ------
__global__ __launch_bounds__(1024) void k_scan(const unsigned* __restrict__ ecnt,
                                               unsigned* __restrict__ row_ptr,
                                               unsigned* __restrict__ bump) {
    __shared__ unsigned sums[1024];
    const int C = 80;                       // 1000 threads cover 80000 exactly
    int t = threadIdx.x;
    int lo = t * C, hi = min(lo + C, N_NODES);
    unsigned s = 0;
    for (int i = lo; i < hi; ++i) s += ecnt[i];
    sums[t] = s;
    // inclusive Hillis-Steele scan over 1024 partials
    for (int ofs = 1; ofs < 1024; ofs <<= 1) {
        __syncthreads();
        unsigned u = (t >= ofs) ? sums[t - ofs] : 0u;
        __syncthreads();
        sums[t] += u;
    }
    __syncthreads();
    unsigned run = (t == 0) ? 0u : sums[t - 1];   // exclusive base
    for (int i = lo; i < hi; ++i) {
        row_ptr[i] = run;
        bump[i]    = run;
        run += ecnt[i];
    }
    if (t == 1023) row_ptr[N_NODES] = sums[1023]; // == N_EDGE (chunks >=1000 empty)
}

// ---------------- bucket fill: csr[pos] = {src, norm bits} ----------------
__global__ void k_fill(const int* __restrict__ ei, const float* __restrict__ dinv,
                       unsigned* __restrict__ bump, int2* __restrict__ csr) {
    int e = blockIdx.x * blockDim.x + threadIdx.x;
    if (e >= N_EDGE) return;
    int s = ei[e];
    int d = ei[N_EDGE + e];
    float nrm = dinv[s] * dinv[d];
    unsigned pos = atomicAdd(&bump[d], 1u);
    csr[pos] = make_int2(s, __float_as_int(nrm));
}

// ---------------- GEMM1: xW1 = x @ W1 ----------------
__global__ __launch_bounds__(256) void k_gemm1(
        const float* __restrict__ x, const float* __restrict__ W1,
        float* __restrict__ xW1) {
    __shared__ float W1s[IN_DIM * H1];   // 16 KB
    int tid = threadIdx.x;
    for (int i = tid; i < IN_DIM * H1; i += 256) W1s[i] = W1[i];
    __syncthreads();
    int r = tid >> 5, c = tid & 31;
    int row = blockIdx.x * 8 + r;
    if (row >= N_NODES) return;
    const float4* x4 = reinterpret_cast<const float4*>(x + (long long)row * IN_DIM);
    float acc = 0.f;
#pragma unroll
    for (int j = 0; j < IN_DIM / 4; ++j) {
        float4 xv = x4[j];
        acc += xv.x * W1s[(4 * j + 0) * H1 + c];
        acc += xv.y * W1s[(4 * j + 1) * H1 + c];
        acc += xv.z * W1s[(4 * j + 2) * H1 + c];
        acc += xv.w * W1s[(4 * j + 3) * H1 + c];
    }
    xW1[row * H1 + c] = acc;
}

// ------- gather layer 1: agg1[d] = sum_e xW1[src_e]*norm_e + xW1[d]*dinv^2 --
// One wave per node. Lanes 0-31 take even edges, 32-63 odd edges (same
// feature f = lane&31); each lane loads csr[j] directly (uniform address per
// half-wave -> broadcast). No variable-lane shuffles.
__global__ __launch_bounds__(256) void k_gather1(
        const unsigned* __restrict__ row_ptr, const int2* __restrict__ csr,
        const float* __restrict__ xW1, const float* __restrict__ dinv,
        float* __restrict__ agg1) {
    int wave = threadIdx.x >> 6;
    int lane = threadIdx.x & 63;
    int f = lane & 31, sub = lane >> 5;
    int d = blockIdx.x * 4 + wave;
    if (d >= N_NODES) return;
    unsigned beg = row_ptr[d], end = row_ptr[d + 1];
    float acc = 0.f;
    for (unsigned j = beg + (unsigned)sub; j < end; j += 2) {
        int2 en = csr[j];
        acc += xW1[en.x * H1 + f] * __int_as_float(en.y);
    }
    acc += __shfl_xor(acc, 32, 64);
    if (lane < 32) {
        float dv = dinv[d];
        agg1[d * H1 + lane] = acc + xW1[d * H1 + lane] * dv * dv;
    }
}

// ---------------- GEMM2: h2 = relu(agg1+b1) @ W2 ----------------
__global__ __launch_bounds__(256) void k_gemm2(
        const float* __restrict__ agg1, const float* __restrict__ b1,
        const float* __restrict__ W2, float* __restrict__ h2) {
    __shared__ float W2s[H1 * H2];   // 8 KB
    __shared__ float b1s[H1];
    int tid = threadIdx.x;
    for (int i = tid; i < H1 * H2; i += 256) W2s[i] = W2[i];
    if (tid < H1) b1s[tid] = b1[tid];
    __syncthreads();
    int r = tid >> 6, c = tid & 63;
    int row = blockIdx.x * 4 + r;
    if (row >= N_NODES) return;
    float acc = 0.f;
#pragma unroll
    for (int k = 0; k < H1; ++k) {
        float hk = fmaxf(agg1[row * H1 + k] + b1s[k], 0.f);
        acc += hk * W2s[k * H2 + c];
    }
    h2[row * H2 + c] = acc;
}

// ------- gather layer 2 FUSED with readout -------
// agg2_row[lane] = sum_e h2[src_e]*norm_e + h2[d]*dinv^2   (in registers)
// then partial[d/NPB] += sum_lane relu(agg2_row + b2) * Wout[(d%NPB)*H2+lane]
__global__ __launch_bounds__(256) void k_gather2_final(
        const unsigned* __restrict__ row_ptr, const int2* __restrict__ csr,
        const float* __restrict__ h2, const float* __restrict__ dinv,
        const float* __restrict__ b2, const float* __restrict__ Wout,
        double* __restrict__ partial) {
    int wave = threadIdx.x >> 6;
    int lane = threadIdx.x & 63;
    int d = blockIdx.x * 4 + wave;
    if (d >= N_NODES) return;
    unsigned beg = row_ptr[d], end = row_ptr[d + 1];
    float acc = 0.f;
    for (unsigned j = beg; j < end; ++j) {
        int2 en = csr[j];                      // wave-uniform address -> broadcast
        acc += h2[en.x * H2 + lane] * __int_as_float(en.y);
    }
    float dv = dinv[d];
    acc += h2[d * H2 + lane] * dv * dv;
    float val = fmaxf(acc + b2[lane], 0.f) * Wout[(d % NPB) * H2 + lane];
    double dval = (double)val;
    for (int off = 32; off; off >>= 1) dval += __shfl_down(dval, off, 64);
    if (lane == 0) unsafeAtomicAdd(&partial[d / NPB], dval);
}

// ---------------- write out ----------------
__global__ void k_out(const double* __restrict__ partial,
                      const float* __restrict__ bout, float* __restrict__ out) {
    int b = threadIdx.x;
    if (b < NB) out[b] = (float)(partial[b] + (double)bout[0]);
}

extern "C" void kernel_launch(void* const* d_in, const int* in_sizes, int n_in,
                              void* d_out, int out_size, void* d_ws, size_t ws_size,
                              hipStream_t stream) {
    const float* x    = (const float*)d_in[0];
    const int*   ei   = (const int*)d_in[1];    // int32 (JAX x64 disabled)
    const float* W1   = (const float*)d_in[2];
    const float* b1   = (const float*)d_in[3];
    const float* W2   = (const float*)d_in[4];
    const float* b2   = (const float*)d_in[5];
    const float* Wout = (const float*)d_in[6];
    const float* bout = (const float*)d_in[7];
    float* out = (float*)d_out;

    // workspace layout — no aliasing, total ~62.7 MB
    char* ws = (char*)d_ws;
    size_t off = 0;
    int2*     csr    = (int2*)(ws + off);     off += (size_t)N_EDGE * 8;        // 20.48 MB
    float*    xW1    = (float*)(ws + off);    off += (size_t)N_NODES * H1 * 4;  // 10.24 MB
    float*    agg1   = (float*)(ws + off);    off += (size_t)N_NODES * H1 * 4;  // 10.24 MB
    float*    h2     = (float*)(ws + off);    off += (size_t)N_NODES * H2 * 4;  // 20.48 MB
    unsigned* ecnt   = (unsigned*)(ws + off); off += (size_t)N_NODES * 4;       // 0.32 MB
    unsigned* row_ptr= (unsigned*)(ws + off); off += (size_t)(N_NODES + 16) * 4;// 0.32 MB
    unsigned* bump   = (unsigned*)(ws + off); off += (size_t)N_NODES * 4;       // 0.32 MB
    float*    dinv   = (float*)(ws + off);    off += (size_t)N_NODES * 4;       // 0.32 MB
    double*   partial= (double*)(ws + off);   off += NB * 8;
    (void)ws_size; (void)in_sizes; (void)n_in; (void)out_size;

    const int B = 256;
    k_init<<<(N_NODES + B - 1) / B, B, 0, stream>>>(ecnt, partial);
    k_deg<<<(N_EDGE + B - 1) / B, B, 0, stream>>>(ei, ecnt);
    k_dinv<<<(N_NODES + B - 1) / B, B, 0, stream>>>(ecnt, dinv);
    k_scan<<<1, 1024, 0, stream>>>(ecnt, row_ptr, bump);
    k_fill<<<(N_EDGE + B - 1) / B, B, 0, stream>>>(ei, dinv, bump, csr);

    k_gemm1<<<N_NODES / 8, B, 0, stream>>>(x, W1, xW1);
    k_gather1<<<N_NODES / 4, B, 0, stream>>>(row_ptr, csr, xW1, dinv, agg1);
    k_gemm2<<<N_NODES / 4, B, 0, stream>>>(agg1, b1, W2, h2);
    k_gather2_final<<<N_NODES / 4, B, 0, stream>>>(row_ptr, csr, h2, dinv, b2, Wout, partial);

    k_out<<<1, 64, 0, stream>>>(partial, bout, out);
}

// Round 5
// 1529.546 us; speedup vs baseline: 1.0406x; 1.0406x over previous
//
#include <hip/hip_runtime.h>

// Problem constants (match reference)
constexpr int   N_NODES = 80000;
constexpr int   N_EDGE  = 2560000;
constexpr int   IN_DIM  = 128;
constexpr int   H1      = 32;
constexpr int   H2      = 64;
constexpr int   NPB     = 10000;   // nodes per batch
constexpr int   NB      = 8;       // batches

// ---------------- init: ecnt = 0, partial = 0 ----------------
__global__ void k_init(unsigned* __restrict__ ecnt, double* __restrict__ partial) {
    int i = blockIdx.x * blockDim.x + threadIdx.x;
    if (i < N_NODES) ecnt[i] = 0u;
    if (i < NB) partial[i] = 0.0;
}

// ---------------- degree count (edges only): ecnt[dst]++ ----------------
__global__ void k_deg(const int* __restrict__ ei, unsigned* __restrict__ ecnt) {
    int e = blockIdx.x * blockDim.x + threadIdx.x;
    if (e >= N_EDGE) return;
    atomicAdd(&ecnt[ei[N_EDGE + e]], 1u);
}

// ---------------- dinv = rsqrt(ecnt + 1)  (+1 = self loop) ----------------
__global__ void k_dinv(const unsigned* __restrict__ ecnt, float* __restrict__ dinv) {
    int i = blockIdx.x * blockDim.x + threadIdx.x;
    if (i < N_NODES) dinv[i] = rsqrtf((float)(ecnt[i] + 1u));
}

// ------- exclusive scan of ecnt -> row_ptr, bump (single block, C=80) ------
__global__ __launch_bounds__(1024) void k_scan(const unsigned* __restrict__ ecnt,
                                               unsigned* __restrict__ row_ptr,
                                               unsigned* __restrict__ bump) {
    __shared__ unsigned sums[1024];
    const int C = 80;                       // 1000 threads cover 80000 exactly
    int t = threadIdx.x;
    int lo = t * C, hi = min(lo + C, N_NODES);
    unsigned s = 0;
    for (int i = lo; i < hi; ++i) s += ecnt[i];
    sums[t] = s;
    // inclusive Hillis-Steele scan over 1024 partials
    for (int ofs = 1; ofs < 1024; ofs <<= 1) {
        __syncthreads();
        unsigned u = (t >= ofs) ? sums[t - ofs] : 0u;
        __syncthreads();
        sums[t] += u;
    }
    __syncthreads();
    unsigned run = (t == 0) ? 0u : sums[t - 1];   // exclusive base
    for (int i = lo; i < hi; ++i) {
        row_ptr[i] = run;
        bump[i]    = run;
        run += ecnt[i];
    }
    if (t == 1023) row_ptr[N_NODES] = sums[1023]; // == N_EDGE
}

// ---------------- bucket fill: csr[pos] = {src, norm bits} ----------------
__global__ void k_fill(const int* __restrict__ ei, const float* __restrict__ dinv,
                       unsigned* __restrict__ bump, int2* __restrict__ csr) {
    int e = blockIdx.x * blockDim.x + threadIdx.x;
    if (e >= N_EDGE) return;
    int s = ei[e];
    int d = ei[N_EDGE + e];
    float nrm = dinv[s] * dinv[d];
    unsigned pos = atomicAdd(&bump[d], 1u);
    csr[pos] = make_int2(s, __float_as_int(nrm));
}

// ---------------- GEMM1: xW1 = x @ W1 ----------------
__global__ __launch_bounds__(256) void k_gemm1(
        const float* __restrict__ x, const float* __restrict__ W1,
        float* __restrict__ xW1) {
    __shared__ float W1s[IN_DIM * H1];   // 16 KB
    int tid = threadIdx.x;
    for (int i = tid; i < IN_DIM * H1; i += 256) W1s[i] = W1[i];
    __syncthreads();
    int r = tid >> 5, c = tid & 31;
    int row = blockIdx.x * 8 + r;
    if (row >= N_NODES) return;
    const float4* x4 = reinterpret_cast<const float4*>(x + (long long)row * IN_DIM);
    float acc = 0.f;
#pragma unroll
    for (int j = 0; j < IN_DIM / 4; ++j) {
        float4 xv = x4[j];
        acc += xv.x * W1s[(4 * j + 0) * H1 + c];
        acc += xv.y * W1s[(4 * j + 1) * H1 + c];
        acc += xv.z * W1s[(4 * j + 2) * H1 + c];
        acc += xv.w * W1s[(4 * j + 3) * H1 + c];
    }
    xW1[row * H1 + c] = acc;
}

// ------- gather layer 1: agg1[d] = sum_e xW1[src_e]*norm_e + xW1[d]*dinv^2 --
// One wave per node; half-waves take even/odd edges (f = lane&31).
// Unroll 4 per half-wave -> 8 edge records + 8 row loads in flight per wave.
__global__ __launch_bounds__(256) void k_gather1(
        const unsigned* __restrict__ row_ptr, const int2* __restrict__ csr,
        const float* __restrict__ xW1, const float* __restrict__ dinv,
        float* __restrict__ agg1) {
    int wave = threadIdx.x >> 6;
    int lane = threadIdx.x & 63;
    int f = lane & 31, sub = lane >> 5;
    int d = blockIdx.x * 4 + wave;
    if (d >= N_NODES) return;
    unsigned beg = row_ptr[d], end = row_ptr[d + 1];
    float acc = 0.f;
    unsigned j = beg + (unsigned)sub;
    // process 4 edges per half-wave per trip (stride 2 within half-wave)
    while (j + 6 < end) {
        int2 e0 = csr[j];
        int2 e1 = csr[j + 2];
        int2 e2 = csr[j + 4];
        int2 e3 = csr[j + 6];
        float v0 = xW1[e0.x * H1 + f] * __int_as_float(e0.y);
        float v1 = xW1[e1.x * H1 + f] * __int_as_float(e1.y);
        float v2 = xW1[e2.x * H1 + f] * __int_as_float(e2.y);
        float v3 = xW1[e3.x * H1 + f] * __int_as_float(e3.y);
        acc += (v0 + v1) + (v2 + v3);
        j += 8;
    }
    while (j < end) {
        int2 en = csr[j];
        acc += xW1[en.x * H1 + f] * __int_as_float(en.y);
        j += 2;
    }
    acc += __shfl_xor(acc, 32, 64);
    if (lane < 32) {
        float dv = dinv[d];
        agg1[d * H1 + lane] = acc + xW1[d * H1 + lane] * dv * dv;
    }
}

// ---------------- GEMM2: h2 = relu(agg1+b1) @ W2 ----------------
__global__ __launch_bounds__(256) void k_gemm2(
        const float* __restrict__ agg1, const float* __restrict__ b1,
        const float* __restrict__ W2, float* __restrict__ h2) {
    __shared__ float W2s[H1 * H2];   // 8 KB
    __shared__ float b1s[H1];
    int tid = threadIdx.x;
    for (int i = tid; i < H1 * H2; i += 256) W2s[i] = W2[i];
    if (tid < H1) b1s[tid] = b1[tid];
    __syncthreads();
    int r = tid >> 6, c = tid & 63;
    int row = blockIdx.x * 4 + r;
    if (row >= N_NODES) return;
    float acc = 0.f;
#pragma unroll
    for (int k = 0; k < H1; ++k) {
        float hk = fmaxf(agg1[row * H1 + k] + b1s[k], 0.f);
        acc += hk * W2s[k * H2 + c];
    }
    h2[row * H2 + c] = acc;
}

// ------- gather layer 2 FUSED with readout -------
// agg2_row[lane] = sum_e h2[src_e]*norm_e + h2[d]*dinv^2   (in registers)
// then partial[d/NPB] += sum_lane relu(agg2_row + b2) * Wout[(d%NPB)*H2+lane]
// Unroll 8: 8 csr entries + 8 h2 row loads in flight per wave.
__global__ __launch_bounds__(256) void k_gather2_final(
        const unsigned* __restrict__ row_ptr, const int2* __restrict__ csr,
        const float* __restrict__ h2, const float* __restrict__ dinv,
        const float* __restrict__ b2, const float* __restrict__ Wout,
        double* __restrict__ partial) {
    int wave = threadIdx.x >> 6;
    int lane = threadIdx.x & 63;
    int d = blockIdx.x * 4 + wave;
    if (d >= N_NODES) return;
    unsigned beg = row_ptr[d], end = row_ptr[d + 1];
    float acc = 0.f;
    unsigned j = beg;
    while (j + 8 <= end) {
        int2 e0 = csr[j + 0];
        int2 e1 = csr[j + 1];
        int2 e2 = csr[j + 2];
        int2 e3 = csr[j + 3];
        int2 e4 = csr[j + 4];
        int2 e5 = csr[j + 5];
        int2 e6 = csr[j + 6];
        int2 e7 = csr[j + 7];
        float v0 = h2[e0.x * H2 + lane] * __int_as_float(e0.y);
        float v1 = h2[e1.x * H2 + lane] * __int_as_float(e1.y);
        float v2 = h2[e2.x * H2 + lane] * __int_as_float(e2.y);
        float v3 = h2[e3.x * H2 + lane] * __int_as_float(e3.y);
        float v4 = h2[e4.x * H2 + lane] * __int_as_float(e4.y);
        float v5 = h2[e5.x * H2 + lane] * __int_as_float(e5.y);
        float v6 = h2[e6.x * H2 + lane] * __int_as_float(e6.y);
        float v7 = h2[e7.x * H2 + lane] * __int_as_float(e7.y);
        acc += ((v0 + v1) + (v2 + v3)) + ((v4 + v5) + (v6 + v7));
        j += 8;
    }
    while (j < end) {
        int2 en = csr[j];
        acc += h2[en.x * H2 + lane] * __int_as_float(en.y);
        ++j;
    }
    float dv = dinv[d];
    acc += h2[d * H2 + lane] * dv * dv;
    float val = fmaxf(acc + b2[lane], 0.f) * Wout[(d % NPB) * H2 + lane];
    double dval = (double)val;
    for (int off = 32; off; off >>= 1) dval += __shfl_down(dval, off, 64);
    if (lane == 0) unsafeAtomicAdd(&partial[d / NPB], dval);
}

// ---------------- write out ----------------
__global__ void k_out(const double* __restrict__ partial,
                      const float* __restrict__ bout, float* __restrict__ out) {
    int b = threadIdx.x;
    if (b < NB) out[b] = (float)(partial[b] + (double)bout[0]);
}

extern "C" void kernel_launch(void* const* d_in, const int* in_sizes, int n_in,
                              void* d_out, int out_size, void* d_ws, size_t ws_size,
                              hipStream_t stream) {
    const float* x    = (const float*)d_in[0];
    const int*   ei   = (const int*)d_in[1];    // int32 (JAX x64 disabled)
    const float* W1   = (const float*)d_in[2];
    const float* b1   = (const float*)d_in[3];
    const float* W2   = (const float*)d_in[4];
    const float* b2   = (const float*)d_in[5];
    const float* Wout = (const float*)d_in[6];
    const float* bout = (const float*)d_in[7];
    float* out = (float*)d_out;

    // workspace layout — no aliasing, total ~62.7 MB
    char* ws = (char*)d_ws;
    size_t off = 0;
    int2*     csr    = (int2*)(ws + off);     off += (size_t)N_EDGE * 8;        // 20.48 MB
    float*    xW1    = (float*)(ws + off);    off += (size_t)N_NODES * H1 * 4;  // 10.24 MB
    float*    agg1   = (float*)(ws + off);    off += (size_t)N_NODES * H1 * 4;  // 10.24 MB
    float*    h2     = (float*)(ws + off);    off += (size_t)N_NODES * H2 * 4;  // 20.48 MB
    unsigned* ecnt   = (unsigned*)(ws + off); off += (size_t)N_NODES * 4;       // 0.32 MB
    unsigned* row_ptr= (unsigned*)(ws + off); off += (size_t)(N_NODES + 16) * 4;// 0.32 MB
    unsigned* bump   = (unsigned*)(ws + off); off += (size_t)N_NODES * 4;       // 0.32 MB
    float*    dinv   = (float*)(ws + off);    off += (size_t)N_NODES * 4;       // 0.32 MB
    double*   partial= (double*)(ws + off);   off += NB * 8;
    (void)ws_size; (void)in_sizes; (void)n_in; (void)out_size;

    const int B = 256;
    k_init<<<(N_NODES + B - 1) / B, B, 0, stream>>>(ecnt, partial);
    k_deg<<<(N_EDGE + B - 1) / B, B, 0, stream>>>(ei, ecnt);
    k_dinv<<<(N_NODES + B - 1) / B, B, 0, stream>>>(ecnt, dinv);
    k_scan<<<1, 1024, 0, stream>>>(ecnt, row_ptr, bump);
    k_fill<<<(N_EDGE + B - 1) / B, B, 0, stream>>>(ei, dinv, bump, csr);

    k_gemm1<<<N_NODES / 8, B, 0, stream>>>(x, W1, xW1);
    k_gather1<<<N_NODES / 4, B, 0, stream>>>(row_ptr, csr, xW1, dinv, agg1);
    k_gemm2<<<N_NODES / 4, B, 0, stream>>>(agg1, b1, W2, h2);
    k_gather2_final<<<N_NODES / 4, B, 0, stream>>>(row_ptr, csr, h2, dinv, b2, Wout, partial);

    k_out<<<1, 64, 0, stream>>>(partial, bout, out);
}

// Round 6
// 1509.077 us; speedup vs baseline: 1.0547x; 1.0136x over previous
//
#include <hip/hip_runtime.h>

// Problem constants (match reference)
constexpr int   N_NODES = 80000;
constexpr int   N_EDGE  = 2560000;
constexpr int   IN_DIM  = 128;
constexpr int   H1      = 32;
constexpr int   H2      = 64;
constexpr int   NPB     = 10000;   // nodes per batch
constexpr int   NB      = 8;       // batches

// ---------------- init: ecnt = 0, partial = 0 ----------------
__global__ void k_init(unsigned* __restrict__ ecnt, double* __restrict__ partial) {
    int i = blockIdx.x * blockDim.x + threadIdx.x;
    if (i < N_NODES) ecnt[i] = 0u;
    if (i < NB) partial[i] = 0.0;
}

// ---------------- degree count (edges only): ecnt[dst]++ ----------------
__global__ void k_deg(const int* __restrict__ ei, unsigned* __restrict__ ecnt) {
    int e = blockIdx.x * blockDim.x + threadIdx.x;
    if (e >= N_EDGE) return;
    atomicAdd(&ecnt[ei[N_EDGE + e]], 1u);
}

// ---------------- dinv = rsqrt(ecnt + 1)  (+1 = self loop) ----------------
__global__ void k_dinv(const unsigned* __restrict__ ecnt, float* __restrict__ dinv) {
    int i = blockIdx.x * blockDim.x + threadIdx.x;
    if (i < N_NODES) dinv[i] = rsqrtf((float)(ecnt[i] + 1u));
}

// ------- exclusive scan of ecnt -> row_ptr, bump (single block, C=80) ------
__global__ __launch_bounds__(1024) void k_scan(const unsigned* __restrict__ ecnt,
                                               unsigned* __restrict__ row_ptr,
                                               unsigned* __restrict__ bump) {
    __shared__ unsigned sums[1024];
    const int C = 80;                       // 1000 threads cover 80000 exactly
    int t = threadIdx.x;
    int lo = t * C, hi = min(lo + C, N_NODES);
    unsigned s = 0;
    for (int i = lo; i < hi; ++i) s += ecnt[i];
    sums[t] = s;
    // inclusive Hillis-Steele scan over 1024 partials
    for (int ofs = 1; ofs < 1024; ofs <<= 1) {
        __syncthreads();
        unsigned u = (t >= ofs) ? sums[t - ofs] : 0u;
        __syncthreads();
        sums[t] += u;
    }
    __syncthreads();
    unsigned run = (t == 0) ? 0u : sums[t - 1];   // exclusive base
    for (int i = lo; i < hi; ++i) {
        row_ptr[i] = run;
        bump[i]    = run;
        run += ecnt[i];
    }
    if (t == 1023) row_ptr[N_NODES] = sums[1023]; // == N_EDGE
}

// ---------------- bucket fill: csr[pos] = {src, norm bits} ----------------
__global__ void k_fill(const int* __restrict__ ei, const float* __restrict__ dinv,
                       unsigned* __restrict__ bump, int2* __restrict__ csr) {
    int e = blockIdx.x * blockDim.x + threadIdx.x;
    if (e >= N_EDGE) return;
    int s = ei[e];
    int d = ei[N_EDGE + e];
    float nrm = dinv[s] * dinv[d];
    unsigned pos = atomicAdd(&bump[d], 1u);
    csr[pos] = make_int2(s, __float_as_int(nrm));
}

// ---------------- GEMM1: xW1 = x @ W1 ----------------
__global__ __launch_bounds__(256) void k_gemm1(
        const float* __restrict__ x, const float* __restrict__ W1,
        float* __restrict__ xW1) {
    __shared__ float W1s[IN_DIM * H1];   // 16 KB
    int tid = threadIdx.x;
    for (int i = tid; i < IN_DIM * H1; i += 256) W1s[i] = W1[i];
    __syncthreads();
    int r = tid >> 5, c = tid & 31;
    int row = blockIdx.x * 8 + r;
    if (row >= N_NODES) return;
    const float4* x4 = reinterpret_cast<const float4*>(x + (long long)row * IN_DIM);
    float acc = 0.f;
#pragma unroll
    for (int j = 0; j < IN_DIM / 4; ++j) {
        float4 xv = x4[j];
        acc += xv.x * W1s[(4 * j + 0) * H1 + c];
        acc += xv.y * W1s[(4 * j + 1) * H1 + c];
        acc += xv.z * W1s[(4 * j + 2) * H1 + c];
        acc += xv.w * W1s[(4 * j + 3) * H1 + c];
    }
    xW1[row * H1 + c] = acc;
}

// ------- gather layer 1: agg1[d] = sum_e xW1[src_e]*norm_e + xW1[d]*dinv^2 --
// Octet-wave mapping: o = lane>>3 (edge slot 0..7), t = lane&7 (feature quad).
// One float4 row-load instruction fetches 8 complete 128B rows (1 KB).
// Unroll 2 -> 16 edges per trip, 2 row-load instrs in flight.
__global__ __launch_bounds__(256) void k_gather1(
        const unsigned* __restrict__ row_ptr, const int2* __restrict__ csr,
        const float* __restrict__ xW1, const float* __restrict__ dinv,
        float* __restrict__ agg1) {
    int wave = threadIdx.x >> 6;
    int lane = threadIdx.x & 63;
    int o = lane >> 3, t = lane & 7;
    int d = blockIdx.x * 4 + wave;
    if (d >= N_NODES) return;
    unsigned beg = row_ptr[d], end = row_ptr[d + 1];
    float4 acc = make_float4(0.f, 0.f, 0.f, 0.f);
    for (unsigned j = beg; j < end; j += 16) {
        unsigned j0 = j + (unsigned)o;
        unsigned j1 = j0 + 8u;
        int2 e0 = (j0 < end) ? csr[j0] : make_int2(0, 0);
        int2 e1 = (j1 < end) ? csr[j1] : make_int2(0, 0);
        float4 r0 = *reinterpret_cast<const float4*>(xW1 + (size_t)e0.x * H1 + 4 * t);
        float4 r1 = *reinterpret_cast<const float4*>(xW1 + (size_t)e1.x * H1 + 4 * t);
        float n0 = __int_as_float(e0.y);
        float n1 = __int_as_float(e1.y);
        acc.x += r0.x * n0 + r1.x * n1;
        acc.y += r0.y * n0 + r1.y * n1;
        acc.z += r0.z * n0 + r1.z * n1;
        acc.w += r0.w * n0 + r1.w * n1;
    }
    // combine edge slots: xor 8, 16, 32 (after this every lane holds the total)
#pragma unroll
    for (int m = 8; m <= 32; m <<= 1) {
        acc.x += __shfl_xor(acc.x, m, 64);
        acc.y += __shfl_xor(acc.y, m, 64);
        acc.z += __shfl_xor(acc.z, m, 64);
        acc.w += __shfl_xor(acc.w, m, 64);
    }
    if (lane < 8) {   // o == 0 octet writes the 32-feature row as 8x float4
        float dv = dinv[d];
        float dv2 = dv * dv;
        float4 self = *reinterpret_cast<const float4*>(xW1 + (size_t)d * H1 + 4 * t);
        float4 outv;
        outv.x = acc.x + self.x * dv2;
        outv.y = acc.y + self.y * dv2;
        outv.z = acc.z + self.z * dv2;
        outv.w = acc.w + self.w * dv2;
        *reinterpret_cast<float4*>(agg1 + (size_t)d * H1 + 4 * t) = outv;
    }
}

// ---------------- GEMM2: h2 = relu(agg1+b1) @ W2 ----------------
__global__ __launch_bounds__(256) void k_gemm2(
        const float* __restrict__ agg1, const float* __restrict__ b1,
        const float* __restrict__ W2, float* __restrict__ h2) {
    __shared__ float W2s[H1 * H2];   // 8 KB
    __shared__ float b1s[H1];
    int tid = threadIdx.x;
    for (int i = tid; i < H1 * H2; i += 256) W2s[i] = W2[i];
    if (tid < H1) b1s[tid] = b1[tid];
    __syncthreads();
    int r = tid >> 6, c = tid & 63;
    int row = blockIdx.x * 4 + r;
    if (row >= N_NODES) return;
    float acc = 0.f;
#pragma unroll
    for (int k = 0; k < H1; ++k) {
        float hk = fmaxf(agg1[row * H1 + k] + b1s[k], 0.f);
        acc += hk * W2s[k * H2 + c];
    }
    h2[row * H2 + c] = acc;
}

// ------- gather layer 2 FUSED with readout -------
// Quarter-wave mapping: q = lane>>4 (edge slot 0..3), t = lane&15 (feature quad).
// One float4 row-load instruction fetches 4 complete 256B rows (1 KB).
// Unroll 2 -> 8 edges per trip. Epilogue: relu(acc + self + b2) * Wout,
// wave-reduced in double, one f64 atomic per node.
__global__ __launch_bounds__(256) void k_gather2_final(
        const unsigned* __restrict__ row_ptr, const int2* __restrict__ csr,
        const float* __restrict__ h2, const float* __restrict__ dinv,
        const float* __restrict__ b2, const float* __restrict__ Wout,
        double* __restrict__ partial) {
    int wave = threadIdx.x >> 6;
    int lane = threadIdx.x & 63;
    int q = lane >> 4, t = lane & 15;
    int d = blockIdx.x * 4 + wave;
    if (d >= N_NODES) return;
    unsigned beg = row_ptr[d], end = row_ptr[d + 1];
    float4 acc = make_float4(0.f, 0.f, 0.f, 0.f);
    for (unsigned j = beg; j < end; j += 8) {
        unsigned j0 = j + (unsigned)q;
        unsigned j1 = j0 + 4u;
        int2 e0 = (j0 < end) ? csr[j0] : make_int2(0, 0);
        int2 e1 = (j1 < end) ? csr[j1] : make_int2(0, 0);
        float4 r0 = *reinterpret_cast<const float4*>(h2 + (size_t)e0.x * H2 + 4 * t);
        float4 r1 = *reinterpret_cast<const float4*>(h2 + (size_t)e1.x * H2 + 4 * t);
        float n0 = __int_as_float(e0.y);
        float n1 = __int_as_float(e1.y);
        acc.x += r0.x * n0 + r1.x * n1;
        acc.y += r0.y * n0 + r1.y * n1;
        acc.z += r0.z * n0 + r1.z * n1;
        acc.w += r0.w * n0 + r1.w * n1;
    }
    // combine edge slots: xor 16, 32 (every lane then holds the total)
#pragma unroll
    for (int m = 16; m <= 32; m <<= 1) {
        acc.x += __shfl_xor(acc.x, m, 64);
        acc.y += __shfl_xor(acc.y, m, 64);
        acc.z += __shfl_xor(acc.z, m, 64);
        acc.w += __shfl_xor(acc.w, m, 64);
    }
    // epilogue (valid on all lanes; values duplicated across q)
    float dv = dinv[d];
    float dv2 = dv * dv;
    float4 self = *reinterpret_cast<const float4*>(h2 + (size_t)d * H2 + 4 * t);
    float4 bb   = *reinterpret_cast<const float4*>(b2 + 4 * t);
    float4 ww   = *reinterpret_cast<const float4*>(Wout + (size_t)(d % NPB) * H2 + 4 * t);
    float v0 = fmaxf(acc.x + self.x * dv2 + bb.x, 0.f) * ww.x;
    float v1 = fmaxf(acc.y + self.y * dv2 + bb.y, 0.f) * ww.y;
    float v2 = fmaxf(acc.z + self.z * dv2 + bb.z, 0.f) * ww.z;
    float v3 = fmaxf(acc.w + self.w * dv2 + bb.w, 0.f) * ww.w;
    double dval = (double)v0 + (double)v1 + (double)v2 + (double)v3;
    // sum across t = 0..15 (only lanes 0..15 feed lane 0)
    dval += __shfl_down(dval, 8, 64);
    dval += __shfl_down(dval, 4, 64);
    dval += __shfl_down(dval, 2, 64);
    dval += __shfl_down(dval, 1, 64);
    if (lane == 0) unsafeAtomicAdd(&partial[d / NPB], dval);
}

// ---------------- write out ----------------
__global__ void k_out(const double* __restrict__ partial,
                      const float* __restrict__ bout, float* __restrict__ out) {
    int b = threadIdx.x;
    if (b < NB) out[b] = (float)(partial[b] + (double)bout[0]);
}

extern "C" void kernel_launch(void* const* d_in, const int* in_sizes, int n_in,
                              void* d_out, int out_size, void* d_ws, size_t ws_size,
                              hipStream_t stream) {
    const float* x    = (const float*)d_in[0];
    const int*   ei   = (const int*)d_in[1];    // int32 (JAX x64 disabled)
    const float* W1   = (const float*)d_in[2];
    const float* b1   = (const float*)d_in[3];
    const float* W2   = (const float*)d_in[4];
    const float* b2   = (const float*)d_in[5];
    const float* Wout = (const float*)d_in[6];
    const float* bout = (const float*)d_in[7];
    float* out = (float*)d_out;

    // workspace layout — no aliasing, total ~62.7 MB
    char* ws = (char*)d_ws;
    size_t off = 0;
    int2*     csr    = (int2*)(ws + off);     off += (size_t)N_EDGE * 8;        // 20.48 MB
    float*    xW1    = (float*)(ws + off);    off += (size_t)N_NODES * H1 * 4;  // 10.24 MB
    float*    agg1   = (float*)(ws + off);    off += (size_t)N_NODES * H1 * 4;  // 10.24 MB
    float*    h2     = (float*)(ws + off);    off += (size_t)N_NODES * H2 * 4;  // 20.48 MB
    unsigned* ecnt   = (unsigned*)(ws + off); off += (size_t)N_NODES * 4;       // 0.32 MB
    unsigned* row_ptr= (unsigned*)(ws + off); off += (size_t)(N_NODES + 16) * 4;// 0.32 MB
    unsigned* bump   = (unsigned*)(ws + off); off += (size_t)N_NODES * 4;       // 0.32 MB
    float*    dinv   = (float*)(ws + off);    off += (size_t)N_NODES * 4;       // 0.32 MB
    double*   partial= (double*)(ws + off);   off += NB * 8;
    (void)ws_size; (void)in_sizes; (void)n_in; (void)out_size;

    const int B = 256;
    k_init<<<(N_NODES + B - 1) / B, B, 0, stream>>>(ecnt, partial);
    k_deg<<<(N_EDGE + B - 1) / B, B, 0, stream>>>(ei, ecnt);
    k_dinv<<<(N_NODES + B - 1) / B, B, 0, stream>>>(ecnt, dinv);
    k_scan<<<1, 1024, 0, stream>>>(ecnt, row_ptr, bump);
    k_fill<<<(N_EDGE + B - 1) / B, B, 0, stream>>>(ei, dinv, bump, csr);

    k_gemm1<<<N_NODES / 8, B, 0, stream>>>(x, W1, xW1);
    k_gather1<<<N_NODES / 4, B, 0, stream>>>(row_ptr, csr, xW1, dinv, agg1);
    k_gemm2<<<N_NODES / 4, B, 0, stream>>>(agg1, b1, W2, h2);
    k_gather2_final<<<N_NODES / 4, B, 0, stream>>>(row_ptr, csr, h2, dinv, b2, Wout, partial);

    k_out<<<1, 64, 0, stream>>>(partial, bout, out);
}

// Round 7
// 627.745 us; speedup vs baseline: 2.5355x; 2.4040x over previous
//
#include <hip/hip_runtime.h>

// Problem constants (match reference)
constexpr int   N_NODES = 80000;
constexpr int   N_EDGE  = 2560000;
constexpr int   IN_DIM  = 128;
constexpr int   H1      = 32;
constexpr int   H2      = 64;
constexpr int   NPB     = 10000;   // nodes per batch
constexpr int   NB      = 8;       // batches
constexpr int   G2_BLOCKS = N_NODES / 4;        // 20000 (4 nodes per block)
constexpr int   BLK_PER_BATCH = G2_BLOCKS / NB; // 2500

// ---------------- init: ecnt = 0 ----------------
__global__ void k_init(unsigned* __restrict__ ecnt) {
    int i = blockIdx.x * blockDim.x + threadIdx.x;
    if (i < N_NODES) ecnt[i] = 0u;
}

// ---------------- degree count (edges only): ecnt[dst]++ ----------------
__global__ void k_deg(const int* __restrict__ ei, unsigned* __restrict__ ecnt) {
    int e = blockIdx.x * blockDim.x + threadIdx.x;
    if (e >= N_EDGE) return;
    atomicAdd(&ecnt[ei[N_EDGE + e]], 1u);
}

// ---------------- dinv = rsqrt(ecnt + 1)  (+1 = self loop) ----------------
__global__ void k_dinv(const unsigned* __restrict__ ecnt, float* __restrict__ dinv) {
    int i = blockIdx.x * blockDim.x + threadIdx.x;
    if (i < N_NODES) dinv[i] = rsqrtf((float)(ecnt[i] + 1u));
}

// ------- exclusive scan of ecnt -> row_ptr, bump (single block, C=80) ------
__global__ __launch_bounds__(1024) void k_scan(const unsigned* __restrict__ ecnt,
                                               unsigned* __restrict__ row_ptr,
                                               unsigned* __restrict__ bump) {
    __shared__ unsigned sums[1024];
    const int C = 80;                       // 1000 threads cover 80000 exactly
    int t = threadIdx.x;
    int lo = t * C, hi = min(lo + C, N_NODES);
    unsigned s = 0;
    for (int i = lo; i < hi; ++i) s += ecnt[i];
    sums[t] = s;
    // inclusive Hillis-Steele scan over 1024 partials
    for (int ofs = 1; ofs < 1024; ofs <<= 1) {
        __syncthreads();
        unsigned u = (t >= ofs) ? sums[t - ofs] : 0u;
        __syncthreads();
        sums[t] += u;
    }
    __syncthreads();
    unsigned run = (t == 0) ? 0u : sums[t - 1];   // exclusive base
    for (int i = lo; i < hi; ++i) {
        row_ptr[i] = run;
        bump[i]    = run;
        run += ecnt[i];
    }
    if (t == 1023) row_ptr[N_NODES] = sums[1023]; // == N_EDGE
}

// ---------------- bucket fill: csr[pos] = {src, norm bits} ----------------
__global__ void k_fill(const int* __restrict__ ei, const float* __restrict__ dinv,
                       unsigned* __restrict__ bump, int2* __restrict__ csr) {
    int e = blockIdx.x * blockDim.x + threadIdx.x;
    if (e >= N_EDGE) return;
    int s = ei[e];
    int d = ei[N_EDGE + e];
    float nrm = dinv[s] * dinv[d];
    unsigned pos = atomicAdd(&bump[d], 1u);
    csr[pos] = make_int2(s, __float_as_int(nrm));
}

// ---------------- GEMM1: xW1 = x @ W1 ----------------
__global__ __launch_bounds__(256) void k_gemm1(
        const float* __restrict__ x, const float* __restrict__ W1,
        float* __restrict__ xW1) {
    __shared__ float W1s[IN_DIM * H1];   // 16 KB
    int tid = threadIdx.x;
    for (int i = tid; i < IN_DIM * H1; i += 256) W1s[i] = W1[i];
    __syncthreads();
    int r = tid >> 5, c = tid & 31;
    int row = blockIdx.x * 8 + r;
    if (row >= N_NODES) return;
    const float4* x4 = reinterpret_cast<const float4*>(x + (long long)row * IN_DIM);
    float acc = 0.f;
#pragma unroll
    for (int j = 0; j < IN_DIM / 4; ++j) {
        float4 xv = x4[j];
        acc += xv.x * W1s[(4 * j + 0) * H1 + c];
        acc += xv.y * W1s[(4 * j + 1) * H1 + c];
        acc += xv.z * W1s[(4 * j + 2) * H1 + c];
        acc += xv.w * W1s[(4 * j + 3) * H1 + c];
    }
    xW1[row * H1 + c] = acc;
}

// ------- gather layer 1: agg1[d] = sum_e xW1[src_e]*norm_e + xW1[d]*dinv^2 --
// Octet-wave mapping: o = lane>>3 (edge slot 0..7), t = lane&7 (feature quad).
__global__ __launch_bounds__(256) void k_gather1(
        const unsigned* __restrict__ row_ptr, const int2* __restrict__ csr,
        const float* __restrict__ xW1, const float* __restrict__ dinv,
        float* __restrict__ agg1) {
    int wave = threadIdx.x >> 6;
    int lane = threadIdx.x & 63;
    int o = lane >> 3, t = lane & 7;
    int d = blockIdx.x * 4 + wave;
    if (d >= N_NODES) return;
    unsigned beg = row_ptr[d], end = row_ptr[d + 1];
    float4 acc = make_float4(0.f, 0.f, 0.f, 0.f);
    for (unsigned j = beg; j < end; j += 16) {
        unsigned j0 = j + (unsigned)o;
        unsigned j1 = j0 + 8u;
        int2 e0 = (j0 < end) ? csr[j0] : make_int2(0, 0);
        int2 e1 = (j1 < end) ? csr[j1] : make_int2(0, 0);
        float4 r0 = *reinterpret_cast<const float4*>(xW1 + (size_t)e0.x * H1 + 4 * t);
        float4 r1 = *reinterpret_cast<const float4*>(xW1 + (size_t)e1.x * H1 + 4 * t);
        float n0 = __int_as_float(e0.y);
        float n1 = __int_as_float(e1.y);
        acc.x += r0.x * n0 + r1.x * n1;
        acc.y += r0.y * n0 + r1.y * n1;
        acc.z += r0.z * n0 + r1.z * n1;
        acc.w += r0.w * n0 + r1.w * n1;
    }
    // combine edge slots: xor 8, 16, 32 (after this every lane holds the total)
#pragma unroll
    for (int m = 8; m <= 32; m <<= 1) {
        acc.x += __shfl_xor(acc.x, m, 64);
        acc.y += __shfl_xor(acc.y, m, 64);
        acc.z += __shfl_xor(acc.z, m, 64);
        acc.w += __shfl_xor(acc.w, m, 64);
    }
    if (lane < 8) {   // o == 0 octet writes the 32-feature row as 8x float4
        float dv = dinv[d];
        float dv2 = dv * dv;
        float4 self = *reinterpret_cast<const float4*>(xW1 + (size_t)d * H1 + 4 * t);
        float4 outv;
        outv.x = acc.x + self.x * dv2;
        outv.y = acc.y + self.y * dv2;
        outv.z = acc.z + self.z * dv2;
        outv.w = acc.w + self.w * dv2;
        *reinterpret_cast<float4*>(agg1 + (size_t)d * H1 + 4 * t) = outv;
    }
}

// ---------------- GEMM2: h2 = relu(agg1+b1) @ W2 ----------------
__global__ __launch_bounds__(256) void k_gemm2(
        const float* __restrict__ agg1, const float* __restrict__ b1,
        const float* __restrict__ W2, float* __restrict__ h2) {
    __shared__ float W2s[H1 * H2];   // 8 KB
    __shared__ float b1s[H1];
    int tid = threadIdx.x;
    for (int i = tid; i < H1 * H2; i += 256) W2s[i] = W2[i];
    if (tid < H1) b1s[tid] = b1[tid];
    __syncthreads();
    int r = tid >> 6, c = tid & 63;
    int row = blockIdx.x * 4 + r;
    if (row >= N_NODES) return;
    float acc = 0.f;
#pragma unroll
    for (int k = 0; k < H1; ++k) {
        float hk = fmaxf(agg1[row * H1 + k] + b1s[k], 0.f);
        acc += hk * W2s[k * H2 + c];
    }
    h2[row * H2 + c] = acc;
}

// ------- gather layer 2 FUSED with readout -------
// Quarter-wave mapping: q = lane>>4 (edge slot), t = lane&15 (feature quad).
// Block handles 4 consecutive nodes (same batch: 10000 % 4 == 0); block sum
// goes to partial2[blockIdx.x] as a plain store — NO contended atomics.
__global__ __launch_bounds__(256) void k_gather2_final(
        const unsigned* __restrict__ row_ptr, const int2* __restrict__ csr,
        const float* __restrict__ h2, const float* __restrict__ dinv,
        const float* __restrict__ b2, const float* __restrict__ Wout,
        double* __restrict__ partial2) {
    int wave = threadIdx.x >> 6;
    int lane = threadIdx.x & 63;
    int q = lane >> 4, t = lane & 15;
    int d = blockIdx.x * 4 + wave;
    unsigned beg = row_ptr[d], end = row_ptr[d + 1];
    float4 acc = make_float4(0.f, 0.f, 0.f, 0.f);
    for (unsigned j = beg; j < end; j += 8) {
        unsigned j0 = j + (unsigned)q;
        unsigned j1 = j0 + 4u;
        int2 e0 = (j0 < end) ? csr[j0] : make_int2(0, 0);
        int2 e1 = (j1 < end) ? csr[j1] : make_int2(0, 0);
        float4 r0 = *reinterpret_cast<const float4*>(h2 + (size_t)e0.x * H2 + 4 * t);
        float4 r1 = *reinterpret_cast<const float4*>(h2 + (size_t)e1.x * H2 + 4 * t);
        float n0 = __int_as_float(e0.y);
        float n1 = __int_as_float(e1.y);
        acc.x += r0.x * n0 + r1.x * n1;
        acc.y += r0.y * n0 + r1.y * n1;
        acc.z += r0.z * n0 + r1.z * n1;
        acc.w += r0.w * n0 + r1.w * n1;
    }
    // combine edge slots: xor 16, 32 (every lane then holds the total)
#pragma unroll
    for (int m = 16; m <= 32; m <<= 1) {
        acc.x += __shfl_xor(acc.x, m, 64);
        acc.y += __shfl_xor(acc.y, m, 64);
        acc.z += __shfl_xor(acc.z, m, 64);
        acc.w += __shfl_xor(acc.w, m, 64);
    }
    // epilogue (valid on all lanes; values duplicated across q)
    float dv = dinv[d];
    float dv2 = dv * dv;
    float4 self = *reinterpret_cast<const float4*>(h2 + (size_t)d * H2 + 4 * t);
    float4 bb   = *reinterpret_cast<const float4*>(b2 + 4 * t);
    float4 ww   = *reinterpret_cast<const float4*>(Wout + (size_t)(d % NPB) * H2 + 4 * t);
    float v0 = fmaxf(acc.x + self.x * dv2 + bb.x, 0.f) * ww.x;
    float v1 = fmaxf(acc.y + self.y * dv2 + bb.y, 0.f) * ww.y;
    float v2 = fmaxf(acc.z + self.z * dv2 + bb.z, 0.f) * ww.z;
    float v3 = fmaxf(acc.w + self.w * dv2 + bb.w, 0.f) * ww.w;
    double dval = (double)v0 + (double)v1 + (double)v2 + (double)v3;
    // sum across t = 0..15 within the q==0 quarter (lanes 0..15 feed lane 0)
    dval += __shfl_down(dval, 8, 64);
    dval += __shfl_down(dval, 4, 64);
    dval += __shfl_down(dval, 2, 64);
    dval += __shfl_down(dval, 1, 64);
    __shared__ double sdbl[4];
    if (lane == 0) sdbl[wave] = dval;
    __syncthreads();
    if (threadIdx.x == 0)
        partial2[blockIdx.x] = (sdbl[0] + sdbl[1]) + (sdbl[2] + sdbl[3]);
}

// ------- final reduce: out[b] = sum of partial2[b*2500 .. ) + bout -------
__global__ __launch_bounds__(256) void k_reduce(
        const double* __restrict__ partial2, const float* __restrict__ bout,
        float* __restrict__ out) {
    int b = blockIdx.x;
    int tid = threadIdx.x;
    double acc = 0.0;
    for (int i = tid; i < BLK_PER_BATCH; i += 256)
        acc += partial2[b * BLK_PER_BATCH + i];
    for (int off = 32; off; off >>= 1) acc += __shfl_down(acc, off, 64);
    __shared__ double sred[4];
    if ((tid & 63) == 0) sred[tid >> 6] = acc;
    __syncthreads();
    if (tid == 0)
        out[b] = (float)(((sred[0] + sred[1]) + (sred[2] + sred[3])) + (double)bout[0]);
}

extern "C" void kernel_launch(void* const* d_in, const int* in_sizes, int n_in,
                              void* d_out, int out_size, void* d_ws, size_t ws_size,
                              hipStream_t stream) {
    const float* x    = (const float*)d_in[0];
    const int*   ei   = (const int*)d_in[1];    // int32 (JAX x64 disabled)
    const float* W1   = (const float*)d_in[2];
    const float* b1   = (const float*)d_in[3];
    const float* W2   = (const float*)d_in[4];
    const float* b2   = (const float*)d_in[5];
    const float* Wout = (const float*)d_in[6];
    const float* bout = (const float*)d_in[7];
    float* out = (float*)d_out;

    // workspace layout — no aliasing, total ~63 MB
    char* ws = (char*)d_ws;
    size_t off = 0;
    int2*     csr     = (int2*)(ws + off);     off += (size_t)N_EDGE * 8;        // 20.48 MB
    float*    xW1     = (float*)(ws + off);    off += (size_t)N_NODES * H1 * 4;  // 10.24 MB
    float*    agg1    = (float*)(ws + off);    off += (size_t)N_NODES * H1 * 4;  // 10.24 MB
    float*    h2      = (float*)(ws + off);    off += (size_t)N_NODES * H2 * 4;  // 20.48 MB
    unsigned* ecnt    = (unsigned*)(ws + off); off += (size_t)N_NODES * 4;       // 0.32 MB
    unsigned* row_ptr = (unsigned*)(ws + off); off += (size_t)(N_NODES + 16) * 4;// 0.32 MB
    unsigned* bump    = (unsigned*)(ws + off); off += (size_t)N_NODES * 4;       // 0.32 MB
    float*    dinv    = (float*)(ws + off);    off += (size_t)N_NODES * 4;       // 0.32 MB
    double*   partial2= (double*)(ws + off);   off += (size_t)G2_BLOCKS * 8;     // 0.16 MB
    (void)ws_size; (void)in_sizes; (void)n_in; (void)out_size;

    const int B = 256;
    k_init<<<(N_NODES + B - 1) / B, B, 0, stream>>>(ecnt);
    k_deg<<<(N_EDGE + B - 1) / B, B, 0, stream>>>(ei, ecnt);
    k_dinv<<<(N_NODES + B - 1) / B, B, 0, stream>>>(ecnt, dinv);
    k_scan<<<1, 1024, 0, stream>>>(ecnt, row_ptr, bump);
    k_fill<<<(N_EDGE + B - 1) / B, B, 0, stream>>>(ei, dinv, bump, csr);

    k_gemm1<<<N_NODES / 8, B, 0, stream>>>(x, W1, xW1);
    k_gather1<<<N_NODES / 4, B, 0, stream>>>(row_ptr, csr, xW1, dinv, agg1);
    k_gemm2<<<N_NODES / 4, B, 0, stream>>>(agg1, b1, W2, h2);
    k_gather2_final<<<G2_BLOCKS, B, 0, stream>>>(row_ptr, csr, h2, dinv, b2, Wout, partial2);

    k_reduce<<<NB, B, 0, stream>>>(partial2, bout, out);
}

// Round 8
// 456.320 us; speedup vs baseline: 3.4880x; 1.3757x over previous
//
#include <hip/hip_runtime.h>

// Problem constants (match reference)
constexpr int   N_NODES = 80000;
constexpr int   N_EDGE  = 2560000;
constexpr int   IN_DIM  = 128;
constexpr int   H1      = 32;
constexpr int   H2      = 64;
constexpr int   NPB     = 10000;   // nodes per batch
constexpr int   NB      = 8;       // batches
constexpr int   G2_BLOCKS = N_NODES / 4;        // 20000 (4 nodes per block)
constexpr int   BLK_PER_BATCH = G2_BLOCKS / NB; // 2500
constexpr int   SCAN_B   = 256;
constexpr int   SCAN_NBLK = (N_NODES + SCAN_B - 1) / SCAN_B;  // 313

// ---------------- init: ecnt = 0 ----------------
__global__ void k_init(unsigned* __restrict__ ecnt) {
    int i = blockIdx.x * blockDim.x + threadIdx.x;
    if (i < N_NODES) ecnt[i] = 0u;
}

// ---------------- degree count (edges only): ecnt[dst]++ ----------------
__global__ void k_deg(const int* __restrict__ ei, unsigned* __restrict__ ecnt) {
    int e = blockIdx.x * blockDim.x + threadIdx.x;
    if (e >= N_EDGE) return;
    atomicAdd(&ecnt[ei[N_EDGE + e]], 1u);
}

// ------- scan phase 1: block-local scan + block totals; fused dinv --------
__global__ __launch_bounds__(SCAN_B) void k_scan1(
        const unsigned* __restrict__ ecnt, unsigned* __restrict__ excl,
        unsigned* __restrict__ blocksum, float* __restrict__ dinv) {
    __shared__ unsigned tmp[SCAN_B];
    int t = threadIdx.x;
    int i = blockIdx.x * SCAN_B + t;
    unsigned v = (i < N_NODES) ? ecnt[i] : 0u;
    tmp[t] = v;
    for (int ofs = 1; ofs < SCAN_B; ofs <<= 1) {
        __syncthreads();
        unsigned u = (t >= ofs) ? tmp[t - ofs] : 0u;
        __syncthreads();
        tmp[t] += u;
    }
    __syncthreads();
    if (i < N_NODES) {
        excl[i] = tmp[t] - v;                  // exclusive within block
        dinv[i] = rsqrtf((float)(v + 1u));     // fused: +1 self loop
    }
    if (t == SCAN_B - 1) blocksum[blockIdx.x] = tmp[t];
}

// ------- scan phase 2: scan the 313 block totals in-place (1 block) -------
__global__ __launch_bounds__(512) void k_scan2(unsigned* __restrict__ blocksum) {
    __shared__ unsigned tmp[512];
    int t = threadIdx.x;
    unsigned v = (t < SCAN_NBLK) ? blocksum[t] : 0u;
    tmp[t] = v;
    for (int ofs = 1; ofs < 512; ofs <<= 1) {
        __syncthreads();
        unsigned u = (t >= ofs) ? tmp[t - ofs] : 0u;
        __syncthreads();
        tmp[t] += u;
    }
    __syncthreads();
    if (t < SCAN_NBLK) blocksum[t] = tmp[t] - v;   // exclusive block base
}

// ------- scan phase 3: row_ptr = excl + base; bump = row_ptr --------------
__global__ __launch_bounds__(SCAN_B) void k_scan3(
        const unsigned* __restrict__ excl, const unsigned* __restrict__ blocksum,
        unsigned* __restrict__ row_ptr, unsigned* __restrict__ bump) {
    int i = blockIdx.x * SCAN_B + threadIdx.x;
    if (i < N_NODES) {
        unsigned r = excl[i] + blocksum[blockIdx.x];
        row_ptr[i] = r;
        bump[i]    = r;
    }
    if (i == 0) row_ptr[N_NODES] = (unsigned)N_EDGE;
}

// ---------------- bucket fill: csr[pos] = {src, norm bits} ----------------
__global__ void k_fill(const int* __restrict__ ei, const float* __restrict__ dinv,
                       unsigned* __restrict__ bump, int2* __restrict__ csr) {
    int e = blockIdx.x * blockDim.x + threadIdx.x;
    if (e >= N_EDGE) return;
    int s = ei[e];
    int d = ei[N_EDGE + e];
    float nrm = dinv[s] * dinv[d];
    unsigned pos = atomicAdd(&bump[d], 1u);
    csr[pos] = make_int2(s, __float_as_int(nrm));
}

// ---------------- GEMM1: xW1 = x @ W1 ----------------
__global__ __launch_bounds__(256) void k_gemm1(
        const float* __restrict__ x, const float* __restrict__ W1,
        float* __restrict__ xW1) {
    __shared__ float W1s[IN_DIM * H1];   // 16 KB
    int tid = threadIdx.x;
    for (int i = tid; i < IN_DIM * H1; i += 256) W1s[i] = W1[i];
    __syncthreads();
    int r = tid >> 5, c = tid & 31;
    int row = blockIdx.x * 8 + r;
    if (row >= N_NODES) return;
    const float4* x4 = reinterpret_cast<const float4*>(x + (long long)row * IN_DIM);
    float acc = 0.f;
#pragma unroll
    for (int j = 0; j < IN_DIM / 4; ++j) {
        float4 xv = x4[j];
        acc += xv.x * W1s[(4 * j + 0) * H1 + c];
        acc += xv.y * W1s[(4 * j + 1) * H1 + c];
        acc += xv.z * W1s[(4 * j + 2) * H1 + c];
        acc += xv.w * W1s[(4 * j + 3) * H1 + c];
    }
    xW1[row * H1 + c] = acc;
}

// ------- gather layer 1: agg1[d] = sum_e xW1[src_e]*norm_e + xW1[d]*dinv^2 --
// Octet-wave mapping: o = lane>>3 (edge slot 0..7), t = lane&7 (feature quad).
__global__ __launch_bounds__(256) void k_gather1(
        const unsigned* __restrict__ row_ptr, const int2* __restrict__ csr,
        const float* __restrict__ xW1, const float* __restrict__ dinv,
        float* __restrict__ agg1) {
    int wave = threadIdx.x >> 6;
    int lane = threadIdx.x & 63;
    int o = lane >> 3, t = lane & 7;
    int d = blockIdx.x * 4 + wave;
    if (d >= N_NODES) return;
    unsigned beg = row_ptr[d], end = row_ptr[d + 1];
    float4 acc = make_float4(0.f, 0.f, 0.f, 0.f);
    for (unsigned j = beg; j < end; j += 16) {
        unsigned j0 = j + (unsigned)o;
        unsigned j1 = j0 + 8u;
        int2 e0 = (j0 < end) ? csr[j0] : make_int2(0, 0);
        int2 e1 = (j1 < end) ? csr[j1] : make_int2(0, 0);
        float4 r0 = *reinterpret_cast<const float4*>(xW1 + (size_t)e0.x * H1 + 4 * t);
        float4 r1 = *reinterpret_cast<const float4*>(xW1 + (size_t)e1.x * H1 + 4 * t);
        float n0 = __int_as_float(e0.y);
        float n1 = __int_as_float(e1.y);
        acc.x += r0.x * n0 + r1.x * n1;
        acc.y += r0.y * n0 + r1.y * n1;
        acc.z += r0.z * n0 + r1.z * n1;
        acc.w += r0.w * n0 + r1.w * n1;
    }
#pragma unroll
    for (int m = 8; m <= 32; m <<= 1) {
        acc.x += __shfl_xor(acc.x, m, 64);
        acc.y += __shfl_xor(acc.y, m, 64);
        acc.z += __shfl_xor(acc.z, m, 64);
        acc.w += __shfl_xor(acc.w, m, 64);
    }
    if (lane < 8) {   // o == 0 octet writes the 32-feature row as 8x float4
        float dv = dinv[d];
        float dv2 = dv * dv;
        float4 self = *reinterpret_cast<const float4*>(xW1 + (size_t)d * H1 + 4 * t);
        float4 outv;
        outv.x = acc.x + self.x * dv2;
        outv.y = acc.y + self.y * dv2;
        outv.z = acc.z + self.z * dv2;
        outv.w = acc.w + self.w * dv2;
        *reinterpret_cast<float4*>(agg1 + (size_t)d * H1 + 4 * t) = outv;
    }
}

// ---------------- GEMM2: h2 = relu(agg1+b1) @ W2 ----------------
__global__ __launch_bounds__(256) void k_gemm2(
        const float* __restrict__ agg1, const float* __restrict__ b1,
        const float* __restrict__ W2, float* __restrict__ h2) {
    __shared__ float W2s[H1 * H2];   // 8 KB
    __shared__ float b1s[H1];
    int tid = threadIdx.x;
    for (int i = tid; i < H1 * H2; i += 256) W2s[i] = W2[i];
    if (tid < H1) b1s[tid] = b1[tid];
    __syncthreads();
    int r = tid >> 6, c = tid & 63;
    int row = blockIdx.x * 4 + r;
    if (row >= N_NODES) return;
    float acc = 0.f;
#pragma unroll
    for (int k = 0; k < H1; ++k) {
        float hk = fmaxf(agg1[row * H1 + k] + b1s[k], 0.f);
        acc += hk * W2s[k * H2 + c];
    }
    h2[row * H2 + c] = acc;
}

// ------- gather layer 2 FUSED with readout -------
// Quarter-wave mapping: q = lane>>4 (edge slot), t = lane&15 (feature quad).
// Block = 4 consecutive nodes (same batch; 10000 % 4 == 0); block sum written
// as a plain store to partial2[blockIdx.x] — no contended atomics.
__global__ __launch_bounds__(256) void k_gather2_final(
        const unsigned* __restrict__ row_ptr, const int2* __restrict__ csr,
        const float* __restrict__ h2, const float* __restrict__ dinv,
        const float* __restrict__ b2, const float* __restrict__ Wout,
        double* __restrict__ partial2) {
    int wave = threadIdx.x >> 6;
    int lane = threadIdx.x & 63;
    int q = lane >> 4, t = lane & 15;
    int d = blockIdx.x * 4 + wave;
    unsigned beg = row_ptr[d], end = row_ptr[d + 1];
    float4 acc = make_float4(0.f, 0.f, 0.f, 0.f);
    for (unsigned j = beg; j < end; j += 8) {
        unsigned j0 = j + (unsigned)q;
        unsigned j1 = j0 + 4u;
        int2 e0 = (j0 < end) ? csr[j0] : make_int2(0, 0);
        int2 e1 = (j1 < end) ? csr[j1] : make_int2(0, 0);
        float4 r0 = *reinterpret_cast<const float4*>(h2 + (size_t)e0.x * H2 + 4 * t);
        float4 r1 = *reinterpret_cast<const float4*>(h2 + (size_t)e1.x * H2 + 4 * t);
        float n0 = __int_as_float(e0.y);
        float n1 = __int_as_float(e1.y);
        acc.x += r0.x * n0 + r1.x * n1;
        acc.y += r0.y * n0 + r1.y * n1;
        acc.z += r0.z * n0 + r1.z * n1;
        acc.w += r0.w * n0 + r1.w * n1;
    }
#pragma unroll
    for (int m = 16; m <= 32; m <<= 1) {
        acc.x += __shfl_xor(acc.x, m, 64);
        acc.y += __shfl_xor(acc.y, m, 64);
        acc.z += __shfl_xor(acc.z, m, 64);
        acc.w += __shfl_xor(acc.w, m, 64);
    }
    float dv = dinv[d];
    float dv2 = dv * dv;
    float4 self = *reinterpret_cast<const float4*>(h2 + (size_t)d * H2 + 4 * t);
    float4 bb   = *reinterpret_cast<const float4*>(b2 + 4 * t);
    float4 ww   = *reinterpret_cast<const float4*>(Wout + (size_t)(d % NPB) * H2 + 4 * t);
    float v0 = fmaxf(acc.x + self.x * dv2 + bb.x, 0.f) * ww.x;
    float v1 = fmaxf(acc.y + self.y * dv2 + bb.y, 0.f) * ww.y;
    float v2 = fmaxf(acc.z + self.z * dv2 + bb.z, 0.f) * ww.z;
    float v3 = fmaxf(acc.w + self.w * dv2 + bb.w, 0.f) * ww.w;
    double dval = (double)v0 + (double)v1 + (double)v2 + (double)v3;
    dval += __shfl_down(dval, 8, 64);
    dval += __shfl_down(dval, 4, 64);
    dval += __shfl_down(dval, 2, 64);
    dval += __shfl_down(dval, 1, 64);
    __shared__ double sdbl[4];
    if (lane == 0) sdbl[wave] = dval;
    __syncthreads();
    if (threadIdx.x == 0)
        partial2[blockIdx.x] = (sdbl[0] + sdbl[1]) + (sdbl[2] + sdbl[3]);
}

// ------- final reduce: out[b] = sum of partial2[b*2500 .. ) + bout -------
__global__ __launch_bounds__(256) void k_reduce(
        const double* __restrict__ partial2, const float* __restrict__ bout,
        float* __restrict__ out) {
    int b = blockIdx.x;
    int tid = threadIdx.x;
    double acc = 0.0;
    for (int i = tid; i < BLK_PER_BATCH; i += 256)
        acc += partial2[b * BLK_PER_BATCH + i];
    for (int off = 32; off; off >>= 1) acc += __shfl_down(acc, off, 64);
    __shared__ double sred[4];
    if ((tid & 63) == 0) sred[tid >> 6] = acc;
    __syncthreads();
    if (tid == 0)
        out[b] = (float)(((sred[0] + sred[1]) + (sred[2] + sred[3])) + (double)bout[0]);
}

extern "C" void kernel_launch(void* const* d_in, const int* in_sizes, int n_in,
                              void* d_out, int out_size, void* d_ws, size_t ws_size,
                              hipStream_t stream) {
    const float* x    = (const float*)d_in[0];
    const int*   ei   = (const int*)d_in[1];    // int32 (JAX x64 disabled)
    const float* W1   = (const float*)d_in[2];
    const float* b1   = (const float*)d_in[3];
    const float* W2   = (const float*)d_in[4];
    const float* b2   = (const float*)d_in[5];
    const float* Wout = (const float*)d_in[6];
    const float* bout = (const float*)d_in[7];
    float* out = (float*)d_out;

    // workspace layout — no aliasing, total ~63.5 MB
    char* ws = (char*)d_ws;
    size_t off = 0;
    int2*     csr     = (int2*)(ws + off);     off += (size_t)N_EDGE * 8;        // 20.48 MB
    float*    xW1     = (float*)(ws + off);    off += (size_t)N_NODES * H1 * 4;  // 10.24 MB
    float*    agg1    = (float*)(ws + off);    off += (size_t)N_NODES * H1 * 4;  // 10.24 MB
    float*    h2      = (float*)(ws + off);    off += (size_t)N_NODES * H2 * 4;  // 20.48 MB
    unsigned* ecnt    = (unsigned*)(ws + off); off += (size_t)N_NODES * 4;       // 0.32 MB
    unsigned* row_ptr = (unsigned*)(ws + off); off += (size_t)(N_NODES + 16) * 4;// 0.32 MB
    unsigned* bump    = (unsigned*)(ws + off); off += (size_t)N_NODES * 4;       // 0.32 MB
    float*    dinv    = (float*)(ws + off);    off += (size_t)N_NODES * 4;       // 0.32 MB
    unsigned* excl    = (unsigned*)(ws + off); off += (size_t)N_NODES * 4;       // 0.32 MB
    unsigned* blocksum= (unsigned*)(ws + off); off += 512 * 4;
    double*   partial2= (double*)(ws + off);   off += (size_t)G2_BLOCKS * 8;     // 0.16 MB
    (void)ws_size; (void)in_sizes; (void)n_in; (void)out_size;

    const int B = 256;
    k_init<<<(N_NODES + B - 1) / B, B, 0, stream>>>(ecnt);
    k_deg<<<(N_EDGE + B - 1) / B, B, 0, stream>>>(ei, ecnt);
    k_scan1<<<SCAN_NBLK, SCAN_B, 0, stream>>>(ecnt, excl, blocksum, dinv);
    k_scan2<<<1, 512, 0, stream>>>(blocksum);
    k_scan3<<<SCAN_NBLK, SCAN_B, 0, stream>>>(excl, blocksum, row_ptr, bump);
    k_fill<<<(N_EDGE + B - 1) / B, B, 0, stream>>>(ei, dinv, bump, csr);

    k_gemm1<<<N_NODES / 8, B, 0, stream>>>(x, W1, xW1);
    k_gather1<<<N_NODES / 4, B, 0, stream>>>(row_ptr, csr, xW1, dinv, agg1);
    k_gemm2<<<N_NODES / 4, B, 0, stream>>>(agg1, b1, W2, h2);
    k_gather2_final<<<G2_BLOCKS, B, 0, stream>>>(row_ptr, csr, h2, dinv, b2, Wout, partial2);

    k_reduce<<<NB, B, 0, stream>>>(partial2, bout, out);
}